// Round 12
// baseline (371.558 us; speedup 1.0000x reference)
//
#include <hip/hip_runtime.h>
#include <cstddef>

#define NN 50000
#define NE 400000
#define NH 4
#define NC 121

typedef __attribute__((ext_vector_type(8))) short short8;
typedef __attribute__((ext_vector_type(4))) float f32x4;
typedef __attribute__((ext_vector_type(2))) float f32x2;

// fp32 -> bf16 round-to-nearest-even
static __device__ __forceinline__ unsigned short f2bf(float f) {
    unsigned u = __float_as_uint(f);
    u += 0x7fffu + ((u >> 16) & 1u);
    return (unsigned short)(u >> 16);
}
// dword holding 2 bf16 -> 2 floats
static __device__ __forceinline__ f32x2 bfpair(unsigned u) {
    f32x2 r;
    r.x = __uint_as_float(u << 16);
    r.y = __uint_as_float(u & 0xffff0000u);
    return r;
}
// async global->LDS, 16B per lane; LDS dest = wave-uniform base + lane*16
static __device__ __forceinline__ void load_lds16(const unsigned short* g, unsigned short* l) {
    __builtin_amdgcn_global_load_lds(
        (const __attribute__((address_space(1))) unsigned*)g,
        (__attribute__((address_space(3))) unsigned*)l, 16, 0, 0);
}

// == fused prep: cast_x + BT1 + BT2 + BTcat + wvec3 + sentinels + dst histogram =====
#define PREP_X    3200000            // NN*256/4 float4->ushort4 items
#define PREP_BT1  (PREP_X + 65536)
#define PREP_BT2  (PREP_BT1 + 65536)
#define PREP_CAT  (PREP_BT2 + 131072)
#define PREP_WV   (PREP_CAT + 2048)
#define PREP_SENT (PREP_WV + 256)
#define PREP_END  (PREP_SENT + NE)
__global__ __launch_bounds__(256) void prep_k(const float* __restrict__ h,
                                              const float* __restrict__ W1,
                                              const float* __restrict__ W2,
                                              const float* __restrict__ W3,
                                              const float* __restrict__ al3,
                                              const float* __restrict__ ar3,
                                              const int* __restrict__ dst,
                                              unsigned short* __restrict__ h_bf,
                                              unsigned short* __restrict__ BT1,
                                              unsigned short* __restrict__ BT2,
                                              unsigned short* __restrict__ BTcat,
                                              float* __restrict__ wl3,
                                              float* __restrict__ wr3,
                                              unsigned short* __restrict__ feat_bf,
                                              float* __restrict__ el,
                                              float* __restrict__ el2,
                                              int* __restrict__ deg) {
    int i = blockIdx.x * blockDim.x + threadIdx.x;
    if (i < PREP_X) {
        float4 v = *(const float4*)&h[(size_t)i * 4];
        ushort4 o;
        o.x = f2bf(v.x); o.y = f2bf(v.y); o.z = f2bf(v.z); o.w = f2bf(v.w);
        *(ushort4*)&h_bf[(size_t)i * 4] = o;
    } else if (i < PREP_BT1) {
        int j = i - PREP_X;
        int n = j >> 8, k = j & 255;
        BT1[j] = f2bf(W1[(size_t)k * 256 + n]);
    } else if (i < PREP_BT2) {
        int j = i - PREP_BT1;
        int n = j >> 8, k = j & 255;
        BT2[j] = f2bf(W2[(size_t)k * 256 + n]);
    } else if (i < PREP_CAT) {
        // BTcat[c][kk]: c = class (121, pad to 128 rows), kk = h*256 + k (K=1024)
        // value = 0.25 * W3[k, h*121 + c]  (0.25 = mean over heads, folded in)
        int j = i - PREP_BT2;
        int c = j >> 10, kk = j & 1023;
        int hh = kk >> 8, k = kk & 255;
        float v = (c < NC) ? 0.25f * W3[(size_t)k * 484 + hh * NC + c] : 0.f;
        BTcat[j] = f2bf(v);
    } else if (i < PREP_WV) {
        int j = (i - PREP_CAT) & 1023;
        int sel = (i - PREP_CAT) >> 10;
        int hh = j >> 8, k = j & 255;
        const float* a = sel ? ar3 : al3;
        const float* wrow = W3 + (size_t)k * 484 + hh * NC;
        const float* arow = a + hh * NC;
        float s = 0.f;
        for (int d = 0; d < NC; ++d) s += wrow[d] * arow[d];
        if (sel) wr3[j] = s; else wl3[j] = s;
    } else if (i < PREP_SENT) {
        // sentinel row NN: feat_bf[NN][*] = 0 (pad gathers read zeros);
        // el/el2 row NN = -1e30 (pad logits -> exp = 0, no masking in agg kernels)
        int j = i - PREP_WV;
        feat_bf[(size_t)NN * 256 + j] = 0;
        if (j < 4) {
            el[NN * 4 + j]  = -1e30f;
            el2[NN * 4 + j] = -1e30f;
        }
    } else if (i < PREP_END) {
        atomicAdd(&deg[dst[i - PREP_SENT]], 1);
    }
}

// ====== 8-wave 128x256 MFMA GEMM for layers 1/2 (N=256, K=256): A read ONCE ======
// Wave w computes 64x64 quadrant (wm=(w>>2)*64, wn=(w&3)*64). Fused logit epilogue:
// wave's 64 output cols = one head (head = w&3).
__global__ __launch_bounds__(512) void gemm256(const unsigned short* __restrict__ A,
                                               const unsigned short* __restrict__ BT,
                                               unsigned short* __restrict__ Cb,
                                               const float* __restrict__ al,
                                               const float* __restrict__ ar,
                                               float* __restrict__ el,
                                               float* __restrict__ er,
                                               int M) {
    const int K = 256;
    __shared__ __align__(16) unsigned short Alds[128 * 32];
    __shared__ __align__(16) unsigned short Blds[256 * 32];
    const int tid = threadIdx.x;
    const int wave = tid >> 6;
    const int lane = tid & 63;
    const int quad = lane >> 4;
    const int ml = lane & 15;
    const int m0 = blockIdx.x * 128;
    const int wm0 = (wave >> 2) * 64;
    const int wn0 = (wave & 3) * 64;

    const unsigned short* Ab = A + (size_t)(m0 + wave * 16 + (lane >> 2)) * K + (lane & 3) * 8;
    const unsigned short* Bb = BT + (size_t)(wave * 16 + (lane >> 2)) * K + (lane & 3) * 8;
    unsigned short* AldsW = Alds + wave * 512;
    unsigned short* BldsW = Blds + wave * 512;

    f32x4 acc[4][4] = {};

    for (int k0 = 0; k0 < K; k0 += 32) {
        load_lds16(Ab + k0, AldsW);
        #pragma unroll
        for (int p = 0; p < 2; ++p)
            load_lds16(Bb + (size_t)(p * 128) * K + k0, BldsW + p * 4096);
        __syncthreads();

        short8 af[4], bf[4];
        #pragma unroll
        for (int i = 0; i < 4; ++i)
            af[i] = *(const short8*)&Alds[(wm0 + i * 16 + ml) * 32 + quad * 8];
        #pragma unroll
        for (int j = 0; j < 4; ++j)
            bf[j] = *(const short8*)&Blds[(wn0 + j * 16 + ml) * 32 + quad * 8];
        #pragma unroll
        for (int i = 0; i < 4; ++i)
            #pragma unroll
            for (int j = 0; j < 4; ++j)
                acc[i][j] = __builtin_amdgcn_mfma_f32_16x16x32_bf16(af[i], bf[j], acc[i][j], 0, 0, 0);
        __syncthreads();
    }

    // C/D layout: col = lane&15, row = quad*4 + reg
    #pragma unroll
    for (int i = 0; i < 4; ++i) {
        #pragma unroll
        for (int reg = 0; reg < 4; ++reg) {
            int m = m0 + wm0 + i * 16 + quad * 4 + reg;
            if (m >= M) continue;
            #pragma unroll
            for (int j = 0; j < 4; ++j) {
                int n = wn0 + j * 16 + ml;
                Cb[(size_t)m * 256 + n] = f2bf(acc[i][j][reg]);
            }
        }
    }

    // ---- fused attention logits: wave's 64 cols = head (wave&3) ----
    {
        int head = wave & 3;
        float alv[4], arv[4];
        #pragma unroll
        for (int j = 0; j < 4; ++j) {
            alv[j] = al[head * 64 + j * 16 + ml];
            arv[j] = ar[head * 64 + j * 16 + ml];
        }
        #pragma unroll
        for (int i = 0; i < 4; ++i) {
            #pragma unroll
            for (int reg = 0; reg < 4; ++reg) {
                float sl = 0.f, sr = 0.f;
                #pragma unroll
                for (int j = 0; j < 4; ++j) {
                    float v = acc[i][j][reg];
                    sl += v * alv[j];
                    sr += v * arv[j];
                }
                #pragma unroll
                for (int off = 1; off < 16; off <<= 1) {
                    sl += __shfl_xor(sl, off);
                    sr += __shfl_xor(sr, off);
                }
                int m = m0 + wm0 + i * 16 + quad * 4 + reg;
                if (ml == 0 && m < M) {
                    el[m * 4 + head] = sl;
                    er[m * 4 + head] = sr;
                }
            }
        }
    }
}

// ================= MFMA GEMM (128x128 tile) — used for the K=1024 output GEMM ======
__global__ __launch_bounds__(256) void gemm_bf16(const unsigned short* __restrict__ A,
                                                 const unsigned short* __restrict__ BT,
                                                 float* __restrict__ Cf,
                                                 int M, int Nout, int K) {
    __shared__ __align__(16) unsigned short Alds[128 * 32];
    __shared__ __align__(16) unsigned short Blds[128 * 32];
    const int tid = threadIdx.x;
    const int wave = tid >> 6;
    const int lane = tid & 63;
    const int quad = lane >> 4;
    const int ml = lane & 15;
    const int m0 = blockIdx.x * 128;
    const int n0 = blockIdx.y * 128;
    const int wm0 = (wave >> 1) * 64;
    const int wn0 = (wave & 1) * 64;

    const unsigned short* Ab = A + (size_t)(m0 + wave * 16 + (lane >> 2)) * K + (lane & 3) * 8;
    const unsigned short* Bb = BT + (size_t)(n0 + wave * 16 + (lane >> 2)) * K + (lane & 3) * 8;
    unsigned short* AldsW = Alds + wave * 512;
    unsigned short* BldsW = Blds + wave * 512;

    f32x4 acc[4][4] = {};

    for (int k0 = 0; k0 < K; k0 += 32) {
        #pragma unroll
        for (int p = 0; p < 2; ++p) {
            load_lds16(Ab + (size_t)(p * 64) * K + k0, AldsW + p * 2048);
            load_lds16(Bb + (size_t)(p * 64) * K + k0, BldsW + p * 2048);
        }
        __syncthreads();

        short8 af[4], bf[4];
        #pragma unroll
        for (int i = 0; i < 4; ++i)
            af[i] = *(const short8*)&Alds[(wm0 + i * 16 + ml) * 32 + quad * 8];
        #pragma unroll
        for (int j = 0; j < 4; ++j)
            bf[j] = *(const short8*)&Blds[(wn0 + j * 16 + ml) * 32 + quad * 8];
        #pragma unroll
        for (int i = 0; i < 4; ++i)
            #pragma unroll
            for (int j = 0; j < 4; ++j)
                acc[i][j] = __builtin_amdgcn_mfma_f32_16x16x32_bf16(af[i], bf[j], acc[i][j], 0, 0, 0);
        __syncthreads();
    }

    // C/D layout: col = lane&15, row = quad*4 + reg
    #pragma unroll
    for (int i = 0; i < 4; ++i) {
        #pragma unroll
        for (int reg = 0; reg < 4; ++reg) {
            int m = m0 + wm0 + i * 16 + quad * 4 + reg;
            if (m >= M) continue;
            #pragma unroll
            for (int j = 0; j < 4; ++j) {
                int n = n0 + wn0 + j * 16 + ml;
                if (n < Nout) Cf[(size_t)m * Nout + n] = acc[i][j][reg];
            }
        }
    }
}

// ======= CSR rowptr via block scan + atomic block-base; fills 4-pad slots inline ====
// pad ssrc -> sentinel row NN (feat zeros, el/el2=-1e30 -> weight exp()=0).
__global__ __launch_bounds__(256) void rowptr_k(const int* __restrict__ deg,
                                                int* __restrict__ rowptr,
                                                int* __restrict__ gtotal,
                                                int* __restrict__ ssrc) {
    __shared__ int sh[256];
    __shared__ int base;
    int i = blockIdx.x * 256 + threadIdx.x;
    int d = (i < NN) ? deg[i] : 0;
    int v = (d + 3) & ~3;
    sh[threadIdx.x] = v;
    __syncthreads();
    for (int off = 1; off < 256; off <<= 1) {
        int t = (threadIdx.x >= off) ? sh[threadIdx.x - off] : 0;
        __syncthreads();
        sh[threadIdx.x] += t;
        __syncthreads();
    }
    if (threadIdx.x == 255) base = atomicAdd(gtotal, sh[255]);
    __syncthreads();
    if (i < NN) {
        int rp = base + sh[threadIdx.x] - v;
        rowptr[i] = rp;
        for (int p = d; p < v; ++p)     // <=3 pad slots
            ssrc[rp + p] = NN << 9;     // sentinel row
    }
}

// scatter: stores BYTE-SCALED src (src*512 = row byte offset in 256-ushort tables)
__global__ __launch_bounds__(256) void scatter_k(const int* __restrict__ src,
                                                 const int* __restrict__ dst,
                                                 const int* __restrict__ rowptr,
                                                 int* __restrict__ cursor,
                                                 int* __restrict__ ssrc) {
    int e = blockIdx.x * blockDim.x + threadIdx.x;
    if (e >= NE) return;
    int d = dst[e];
    int p = atomicAdd(&cursor[d], 1);
    ssrc[rowptr[d] + p] = src[e] << 9;
}

// ===== layers 1/2 aggregation: inline weights, sentinel pads (no masking), 4-unroll =
// el3/er3 (fused layer-3 logit outputs) MUST be disjoint from el/er (read here)!
__global__ __launch_bounds__(256) void agg256(const int* __restrict__ rowptr,
                                              const int* __restrict__ deg,
                                              const int* __restrict__ ssrc,
                                              const float* __restrict__ el,
                                              const float* __restrict__ er,
                                              const unsigned short* __restrict__ feat,
                                              unsigned short* __restrict__ ybf,
                                              const float* __restrict__ wl3,
                                              const float* __restrict__ wr3,
                                              float* __restrict__ el3,
                                              float* __restrict__ er3) {
    int wid = (blockIdx.x * blockDim.x + threadIdx.x) >> 6;
    int lane = threadIdx.x & 63;
    if (wid >= NN) return;
    int n = wid;
    int start = rowptr[n];
    int cnt4 = (deg[n] + 3) & ~3;
    int head = lane >> 4;
    float ern = er[n * 4 + head];
    const char* elb = (const char*)el + head * 4;   // + (src*16) per edge
    const char* fbase = (const char*)feat + lane * 8;
    f32x2 a01 = {0.f, 0.f}, a23 = {0.f, 0.f};
    float ssum = 0.f;
    for (int k = 0; k < cnt4; k += 4) {
        int4 sv = *(const int4*)&ssrc[start + k];   // wave-uniform -> scalar loads
        float e0 = *(const float*)(elb + (sv.x >> 5));
        float e1 = *(const float*)(elb + (sv.y >> 5));
        float e2 = *(const float*)(elb + (sv.z >> 5));
        float e3 = *(const float*)(elb + (sv.w >> 5));
        float v0 = e0 + ern; v0 = fmaxf(v0, 0.2f * v0); float w0 = __expf(v0);
        float v1 = e1 + ern; v1 = fmaxf(v1, 0.2f * v1); float w1 = __expf(v1);
        float v2 = e2 + ern; v2 = fmaxf(v2, 0.2f * v2); float w2 = __expf(v2);
        float v3 = e3 + ern; v3 = fmaxf(v3, 0.2f * v3); float w3 = __expf(v3);
        uint2 u0 = *(const uint2*)(fbase + sv.x);
        uint2 u1 = *(const uint2*)(fbase + sv.y);
        uint2 u2 = *(const uint2*)(fbase + sv.z);
        uint2 u3 = *(const uint2*)(fbase + sv.w);
        ssum += (w0 + w1) + (w2 + w3);
        a01 += w0 * bfpair(u0.x); a23 += w0 * bfpair(u0.y);
        a01 += w1 * bfpair(u1.x); a23 += w1 * bfpair(u1.y);
        a01 += w2 * bfpair(u2.x); a23 += w2 * bfpair(u2.y);
        a01 += w3 * bfpair(u3.x); a23 += w3 * bfpair(u3.y);
    }
    float inv = ssum > 0.f ? 1.0f / ssum : 0.f;
    float r0 = a01.x * inv, r1 = a01.y * inv, r2 = a23.x * inv, r3 = a23.y * inv;
    r0 = r0 > 0.f ? r0 : (__expf(r0) - 1.f);
    r1 = r1 > 0.f ? r1 : (__expf(r1) - 1.f);
    r2 = r2 > 0.f ? r2 : (__expf(r2) - 1.f);
    r3 = r3 > 0.f ? r3 : (__expf(r3) - 1.f);
    ushort4 o;
    o.x = f2bf(r0); o.y = f2bf(r1); o.z = f2bf(r2); o.w = f2bf(r3);
    *(ushort4*)&ybf[(size_t)n * 256 + lane * 4] = o;

    // ---- fused layer-3 logits (layer-2 instance only; writes DISJOINT el3/er3) ----
    if (wl3) {
        float sl[4], sr[4];
        #pragma unroll
        for (int h = 0; h < 4; ++h) {
            float4 a4 = *(const float4*)&wl3[h * 256 + lane * 4];
            float4 b4 = *(const float4*)&wr3[h * 256 + lane * 4];
            sl[h] = r0 * a4.x + r1 * a4.y + r2 * a4.z + r3 * a4.w;
            sr[h] = r0 * b4.x + r1 * b4.y + r2 * b4.z + r3 * b4.w;
        }
        #pragma unroll
        for (int off = 32; off; off >>= 1) {
            #pragma unroll
            for (int h = 0; h < 4; ++h) {
                sl[h] += __shfl_xor(sl[h], off);
                sr[h] += __shfl_xor(sr[h], off);
            }
        }
        if (lane == 0) {
            #pragma unroll
            for (int h = 0; h < 4; ++h) {
                el3[n * 4 + h] = sl[h];
                er3[n * 4 + h] = sr[h];
            }
        }
    }
}

// ===== layer 3: aggregate x2 rows -> xagg[N][4][256] bf16, INLINE edge weights =====
// Weights computed once per edge by lane e (parallel), staged in WAVE-PRIVATE LDS,
// then read back with wave-uniform address (ds_read broadcast) — keeps VGPR low
// (round-11's shfl version hit 48 VGPR -> 41% occupancy; LDS staging restores the
// round-10 register profile). Pads hit sentinel row NN (el2=-1e30 -> w=0).
__global__ __launch_bounds__(256) void agg3(const int* __restrict__ rowptr,
                                            const int* __restrict__ deg,
                                            const int* __restrict__ ssrc,
                                            const float* __restrict__ el,
                                            const float* __restrict__ er,
                                            const unsigned short* __restrict__ x,
                                            unsigned short* __restrict__ xagg) {
    __shared__ __align__(16) float wsh[4][64][4];   // [wave][edge][head], 4 KB
    int wave = threadIdx.x >> 6;
    int lane = threadIdx.x & 63;
    int wid = (blockIdx.x * blockDim.x + threadIdx.x) >> 6;
    if (wid >= NN) return;
    int n = wid;
    int start = rowptr[n];
    int cnt4 = (deg[n] + 3) & ~3;
    const char* xbase = (const char*)x + lane * 8;
    float4 ern = *(const float4*)&er[n * 4];
    f32x2 accA[4] = {}, accB[4] = {};
    float ssum[4] = {};
    for (int base = 0; base < cnt4; base += 64) {
        // lane-parallel weight compute for up to 64 edges -> wave-private LDS
        int idx = base + lane;
        if (idx < cnt4) {
            int su = ssrc[start + idx];                       // coalesced
            float4 e4 = *(const float4*)((const char*)el + (su >> 5));
            float v0 = e4.x + ern.x; v0 = fmaxf(v0, 0.2f * v0);
            float v1 = e4.y + ern.y; v1 = fmaxf(v1, 0.2f * v1);
            float v2 = e4.z + ern.z; v2 = fmaxf(v2, 0.2f * v2);
            float v3 = e4.w + ern.w; v3 = fmaxf(v3, 0.2f * v3);
            float4 w4;
            w4.x = __expf(v0); w4.y = __expf(v1); w4.z = __expf(v2); w4.w = __expf(v3);
            *(float4*)wsh[wave][lane] = w4;
        }
        int rem = cnt4 - base;
        int kend = rem > 64 ? 64 : rem;
        for (int k = 0; k < kend; k += 4) {
            int4 sv = *(const int4*)&ssrc[start + base + k];
            float4 wE0 = *(const float4*)wsh[wave][k];      // uniform addr -> broadcast
            float4 wE1 = *(const float4*)wsh[wave][k + 1];
            float4 wE2 = *(const float4*)wsh[wave][k + 2];
            float4 wE3 = *(const float4*)wsh[wave][k + 3];
            uint2 u0 = *(const uint2*)(xbase + sv.x);
            uint2 u1 = *(const uint2*)(xbase + sv.y);
            uint2 u2 = *(const uint2*)(xbase + sv.z);
            uint2 u3 = *(const uint2*)(xbase + sv.w);
            ssum[0] += (wE0.x + wE1.x) + (wE2.x + wE3.x);
            ssum[1] += (wE0.y + wE1.y) + (wE2.y + wE3.y);
            ssum[2] += (wE0.z + wE1.z) + (wE2.z + wE3.z);
            ssum[3] += (wE0.w + wE1.w) + (wE2.w + wE3.w);
            f32x2 fa = bfpair(u0.x), fA = bfpair(u0.y);
            f32x2 fb = bfpair(u1.x), fB = bfpair(u1.y);
            f32x2 fc = bfpair(u2.x), fC = bfpair(u2.y);
            f32x2 fd = bfpair(u3.x), fD = bfpair(u3.y);
            accA[0] += wE0.x * fa + wE1.x * fb + wE2.x * fc + wE3.x * fd;
            accB[0] += wE0.x * fA + wE1.x * fB + wE2.x * fC + wE3.x * fD;
            accA[1] += wE0.y * fa + wE1.y * fb + wE2.y * fc + wE3.y * fd;
            accB[1] += wE0.y * fA + wE1.y * fB + wE2.y * fC + wE3.y * fD;
            accA[2] += wE0.z * fa + wE1.z * fb + wE2.z * fc + wE3.z * fd;
            accB[2] += wE0.z * fA + wE1.z * fB + wE2.z * fC + wE3.z * fD;
            accA[3] += wE0.w * fa + wE1.w * fb + wE2.w * fc + wE3.w * fd;
            accB[3] += wE0.w * fA + wE1.w * fB + wE2.w * fC + wE3.w * fD;
        }
    }
    #pragma unroll
    for (int h = 0; h < 4; ++h) {
        float inv = ssum[h] > 0.f ? 1.f / ssum[h] : 0.f;
        ushort4 o;
        o.x = f2bf(accA[h].x * inv); o.y = f2bf(accA[h].y * inv);
        o.z = f2bf(accB[h].x * inv); o.w = f2bf(accB[h].y * inv);
        *(ushort4*)&xagg[(size_t)n * 1024 + h * 256 + lane * 4] = o;
    }
}

extern "C" void kernel_launch(void* const* d_in, const int* in_sizes, int n_in,
                              void* d_out, int out_size, void* d_ws, size_t ws_size,
                              hipStream_t stream) {
    const float* h   = (const float*)d_in[0];
    const int*   src = (const int*)d_in[1];
    const int*   dst = (const int*)d_in[2];
    const float* W1  = (const float*)d_in[3];
    const float* al1 = (const float*)d_in[4];
    const float* ar1 = (const float*)d_in[5];
    const float* W2  = (const float*)d_in[6];
    const float* al2 = (const float*)d_in[7];
    const float* ar2 = (const float*)d_in[8];
    const float* W3  = (const float*)d_in[9];
    const float* al3 = (const float*)d_in[10];
    const float* ar3 = (const float*)d_in[11];
    float* out = (float*)d_out;

    float* ws = (float*)d_ws;
    unsigned short* x_bf    = (unsigned short*)ws;
    unsigned short* h_bf    = (unsigned short*)(ws + 6400000);
    unsigned short* feat_bf = (unsigned short*)(ws + 12800000);  // +1 sentinel row
    unsigned short* xagg    = (unsigned short*)(ws + 6400000);   // overlays h_bf+feat_bf (dead by L3)
    float* el  = ws + 32000000;                  // 50001 rows x 4 (row NN = sentinel)
    float* er  = ws + 32200064;
    float* wl3 = ws + 32400064;
    float* wr3 = ws + 32401088;
    unsigned short* BT1   = (unsigned short*)(ws + 32402112);
    unsigned short* BT2   = (unsigned short*)(ws + 32434880);
    unsigned short* BTcat = (unsigned short*)(ws + 32467648);
    int* ibase  = (int*)(ws + 32533184);
    int* deg      = ibase;                       // 50,000
    int* cursor   = ibase + 50000;               // 50,000 (adjacent: one memset)
    int* gtotal   = ibase + 100000;              // 1 (same memset range)
    int* rowptr   = ibase + 100256;              // 50,000
    int* ssrc     = ibase + 150256;              // 600,000 (byte-scaled src)
    float* el2 = ws + 33283440;                  // 50001 rows x 4 (row NN = sentinel)
    float* er2 = ws + 33483504;                  // 200,000

    const int NB = (NN + 255) / 256;

    // ---- single memset: deg + cursor + gtotal (pads handled inside rowptr_k) ----
    hipMemsetAsync(deg, 0, (2 * NN + 1) * sizeof(int), stream);

    // ---- fused prep: casts + weight prep + sentinels + dst histogram ----
    prep_k<<<(PREP_END + 255) / 256, 256, 0, stream>>>(h, W1, W2, W3, al3, ar3, dst,
                                                       h_bf, BT1, BT2, BTcat, wl3, wr3,
                                                       feat_bf, el, el2, deg);

    // ---- CSR build: one scan kernel (atomic block base + inline pad-fill) ----
    rowptr_k<<<NB, 256, 0, stream>>>(deg, rowptr, gtotal, ssrc);
    scatter_k<<<(NE + 255) / 256, 256, 0, stream>>>(src, dst, rowptr, cursor, ssrc);

    const int GB = (NN + 127) / 128;             // 391 blocks, full 256-col tile
    const int WAVE_BLOCKS = (NN * 64 + 255) / 256;   // one wave per node

    // ---- layer 1 (agg computes edge weights inline from el/er; sentinel pads) ----
    gemm256<<<GB, 512, 0, stream>>>(h_bf, BT1, feat_bf, al1, ar1, el, er, NN);
    agg256<<<WAVE_BLOCKS, 256, 0, stream>>>(rowptr, deg, ssrc, el, er, feat_bf, x_bf,
                                            nullptr, nullptr, nullptr, nullptr);

    // ---- layer 2 (fused layer-3 logit epilogue -> el2/er2, disjoint) ----
    gemm256<<<GB, 512, 0, stream>>>(x_bf, BT2, feat_bf, al2, ar2, el, er, NN);
    agg256<<<WAVE_BLOCKS, 256, 0, stream>>>(rowptr, deg, ssrc, el, er, feat_bf, x_bf,
                                            wl3, wr3, el2, er2);

    // ---- layer 3 (inline weights via lane-parallel precompute + LDS broadcast) ----
    agg3<<<WAVE_BLOCKS, 256, 0, stream>>>(rowptr, deg, ssrc, el2, er2, x_bf, xagg);
    gemm_bf16<<<dim3(GB, 1), 256, 0, stream>>>(xagg, BTcat, out, NN, NC, 1024);
}